// Round 1
// baseline (357.550 us; speedup 1.0000x reference)
//
#include <hip/hip_runtime.h>

// Problem constants (fixed shape)
#define M_DIM 8192   // B*S = 2*4096
#define N_DIM 4096   // D_OUT
#define K_DIM 4096   // D_IN

typedef __attribute__((ext_vector_type(4))) float f32x4;
using short8 = __attribute__((ext_vector_type(8))) short;

// ---------------------------------------------------------------------------
// Numerics helpers
// ---------------------------------------------------------------------------

// fp32 -> e4m3fn -> fp32 round trip, RNE, handles subnormals (min 2^-9).
__device__ __forceinline__ float e4m3_rt(float f) {
    float a = fabsf(f);
    int e = (int)((__float_as_uint(a) >> 23)) - 127;   // floor(log2 a) for normals; -127 for 0
    if (e < -6) e = -6;                                 // e4m3 subnormal region
    // q = 2^(e-3): quantum; qinv = 2^(3-e). Both exact powers of two.
    float q    = __uint_as_float((unsigned)(e - 3 + 127) << 23);
    float qinv = __uint_as_float((unsigned)(3 - e + 127) << 23);
    float r = rintf(a * qinv) * q;                      // RNE to the e4m3 grid
    if (r > 448.0f) r = 448.0f;                         // saturate (out of range for this data)
    return copysignf(r, f);
}

// fp32 -> bf16 bits, RNE
__device__ __forceinline__ unsigned short f2bf(float f) {
    unsigned u = __float_as_uint(f);
    u += 0x7FFFu + ((u >> 16) & 1u);
    return (unsigned short)(u >> 16);
}

__device__ __forceinline__ void gload_lds16(const unsigned short* g, unsigned short* l) {
    __builtin_amdgcn_global_load_lds(
        (const __attribute__((address_space(1))) void*)g,
        (__attribute__((address_space(3))) void*)l,
        16, 0, 0);
}

// ---------------------------------------------------------------------------
// Conversion pre-passes
// ---------------------------------------------------------------------------

__global__ void cvt_x_kernel(const float* __restrict__ in,
                             unsigned short* __restrict__ outp, long n8) {
    long stride = (long)gridDim.x * blockDim.x;
    for (long i = (long)blockIdx.x * blockDim.x + threadIdx.x; i < n8; i += stride) {
        const float4* p = (const float4*)(in + i * 8);
        float4 v0 = p[0], v1 = p[1];
        uint4 o;
        o.x = (unsigned)f2bf(v0.x) | ((unsigned)f2bf(v0.y) << 16);
        o.y = (unsigned)f2bf(v0.z) | ((unsigned)f2bf(v0.w) << 16);
        o.z = (unsigned)f2bf(v1.x) | ((unsigned)f2bf(v1.y) << 16);
        o.w = (unsigned)f2bf(v1.z) | ((unsigned)f2bf(v1.w) << 16);
        *(uint4*)(outp + i * 8) = o;
    }
}

__global__ void cvt_w_kernel(const float* __restrict__ in,
                             unsigned short* __restrict__ outp, long n8) {
    long stride = (long)gridDim.x * blockDim.x;
    for (long i = (long)blockIdx.x * blockDim.x + threadIdx.x; i < n8; i += stride) {
        const float4* p = (const float4*)(in + i * 8);
        float4 v0 = p[0], v1 = p[1];
        uint4 o;
        o.x = (unsigned)f2bf(e4m3_rt(v0.x)) | ((unsigned)f2bf(e4m3_rt(v0.y)) << 16);
        o.y = (unsigned)f2bf(e4m3_rt(v0.z)) | ((unsigned)f2bf(e4m3_rt(v0.w)) << 16);
        o.z = (unsigned)f2bf(e4m3_rt(v1.x)) | ((unsigned)f2bf(e4m3_rt(v1.y)) << 16);
        o.w = (unsigned)f2bf(e4m3_rt(v1.z)) | ((unsigned)f2bf(e4m3_rt(v1.w)) << 16);
        *(uint4*)(outp + i * 8) = o;
    }
}

// ---------------------------------------------------------------------------
// Main GEMM: m97 structure. 128x128 tile, BK=64, 4 waves (2x2), each wave a
// 64x64 sub-tile = 4x4 fragments of mfma_f32_16x16x32_bf16. Staging via
// global_load_lds width=16, linear LDS layout. C = A(bf16 x) * W^T + bias_q.
// Both A [M][K] and W [N][K] are K-contiguous -> identical frag addressing.
// ---------------------------------------------------------------------------

__global__ void gemm_bf16_kernel(const unsigned short* __restrict__ A,
                                 const unsigned short* __restrict__ Bw,
                                 const float* __restrict__ bias,
                                 float* __restrict__ C) {
    __shared__ __align__(16) unsigned short As[128][64];
    __shared__ __align__(16) unsigned short Bs[128][64];

    // XCD-aware swizzle: nwg = 64*32 = 2048, divisible by 8.
    int bid = blockIdx.x;
    int swz = (bid & 7) * 256 + (bid >> 3);
    int bm0 = (swz >> 5) * 128;   // 64 M-tiles
    int bn0 = (swz & 31) * 128;   // 32 N-tiles

    int tid = threadIdx.x;
    int l   = tid & 63;
    int w   = tid >> 6;
    int wr  = w >> 1, wc = w & 1;
    int l15 = l & 15, hi = l >> 4;

    // Staging addressing: per round j (0..3), wave w stages rows
    // j*32 + w*8 + l/8, cols (l&7)*8 .. +7 of the 128x64 tile.
    const unsigned short* gA = A  + (size_t)(bm0 + w * 8 + (l >> 3)) * K_DIM + (l & 7) * 8;
    const unsigned short* gB = Bw + (size_t)(bn0 + w * 8 + (l >> 3)) * K_DIM + (l & 7) * 8;
    unsigned short* lA = &As[0][0] + w * 512;   // wave-uniform; lane offset is HW (+l*16B)
    unsigned short* lB = &Bs[0][0] + w * 512;

    f32x4 acc[4][4];
#pragma unroll
    for (int m = 0; m < 4; ++m)
#pragma unroll
        for (int n = 0; n < 4; ++n)
            acc[m][n] = (f32x4){0.f, 0.f, 0.f, 0.f};

    for (int kt = 0; kt < K_DIM; kt += 64) {
#pragma unroll
        for (int j = 0; j < 4; ++j) {
            gload_lds16(gA + (size_t)j * 32 * K_DIM + kt, lA + j * 2048);
            gload_lds16(gB + (size_t)j * 32 * K_DIM + kt, lB + j * 2048);
        }
        __syncthreads();   // compiler emits vmcnt(0) drain before s_barrier

#pragma unroll
        for (int kk = 0; kk < 64; kk += 32) {
            short8 af[4], bf_[4];
#pragma unroll
            for (int m = 0; m < 4; ++m)
                af[m] = *(const short8*)&As[wr * 64 + m * 16 + l15][kk + hi * 8];
#pragma unroll
            for (int n = 0; n < 4; ++n)
                bf_[n] = *(const short8*)&Bs[wc * 64 + n * 16 + l15][kk + hi * 8];
#pragma unroll
            for (int m = 0; m < 4; ++m)
#pragma unroll
                for (int n = 0; n < 4; ++n)
                    acc[m][n] = __builtin_amdgcn_mfma_f32_16x16x32_bf16(
                        af[m], bf_[n], acc[m][n], 0, 0, 0);
        }
        __syncthreads();
    }

    // Epilogue: C/D layout col = l&15, row = (l>>4)*4 + reg. Add quantized bias.
    float bq[4];
#pragma unroll
    for (int n = 0; n < 4; ++n)
        bq[n] = e4m3_rt(bias[bn0 + wc * 64 + n * 16 + l15]);

#pragma unroll
    for (int m = 0; m < 4; ++m) {
        int orow = bm0 + wr * 64 + m * 16 + hi * 4;
#pragma unroll
        for (int n = 0; n < 4; ++n) {
            int ocol = bn0 + wc * 64 + n * 16 + l15;
#pragma unroll
            for (int j = 0; j < 4; ++j)
                C[(size_t)(orow + j) * N_DIM + ocol] = acc[m][n][j] + bq[n];
        }
    }
}

// ---------------------------------------------------------------------------
// Fallback (only if ws too small): simple fp32 LDS-tiled GEMM, quantize W on
// the fly. Correctness insurance, not performance.
// ---------------------------------------------------------------------------

__global__ void fb_gemm_kernel(const float* __restrict__ A, const float* __restrict__ W,
                               const float* __restrict__ bias, float* __restrict__ C) {
    __shared__ float As[16][16];
    __shared__ float Ws[16][16];
    int tx = threadIdx.x & 15, ty = threadIdx.x >> 4;
    int row = blockIdx.y * 16 + ty;
    int col = blockIdx.x * 16 + tx;
    float acc = 0.f;
    for (int k0 = 0; k0 < K_DIM; k0 += 16) {
        As[ty][tx] = A[(size_t)row * K_DIM + k0 + tx];
        Ws[ty][tx] = e4m3_rt(W[(size_t)(blockIdx.x * 16 + ty) * K_DIM + k0 + tx]);
        __syncthreads();
#pragma unroll
        for (int kk = 0; kk < 16; ++kk)
            acc += As[ty][kk] * Ws[tx][kk];
        __syncthreads();
    }
    C[(size_t)row * N_DIM + col] = acc + e4m3_rt(bias[col]);
}

// ---------------------------------------------------------------------------

extern "C" void kernel_launch(void* const* d_in, const int* in_sizes, int n_in,
                              void* d_out, int out_size, void* d_ws, size_t ws_size,
                              hipStream_t stream) {
    const float* x  = (const float*)d_in[0];   // [8192, 4096] fp32
    const float* wt = (const float*)d_in[1];   // [4096, 4096] fp32
    const float* bi = (const float*)d_in[2];   // [4096] fp32
    float* out = (float*)d_out;

    const size_t needA = (size_t)M_DIM * K_DIM * 2;  // 67,108,864
    const size_t needW = (size_t)N_DIM * K_DIM * 2;  // 33,554,432

    if (ws_size >= needA + needW) {
        unsigned short* Abf = (unsigned short*)d_ws;
        unsigned short* Wbf = (unsigned short*)((char*)d_ws + needA);

        cvt_x_kernel<<<2048, 256, 0, stream>>>(x, Abf, (long)M_DIM * K_DIM / 8);
        cvt_w_kernel<<<2048, 256, 0, stream>>>(wt, Wbf, (long)N_DIM * K_DIM / 8);

        dim3 grid((M_DIM / 128) * (N_DIM / 128));  // 2048
        gemm_bf16_kernel<<<grid, 256, 0, stream>>>(Abf, Wbf, bi, out);
    } else {
        dim3 grid(N_DIM / 16, M_DIM / 16);
        fb_gemm_kernel<<<grid, 256, 0, stream>>>(x, wt, bi, out);
    }
}

// Round 2
// 296.488 us; speedup vs baseline: 1.2059x; 1.2059x over previous
//
#include <hip/hip_runtime.h>

// Problem constants (fixed shape)
#define M_DIM 8192   // B*S = 2*4096
#define N_DIM 4096   // D_OUT
#define K_DIM 4096   // D_IN
#define NT    (K_DIM / 64)   // 64 K-tiles of BK=64

typedef __attribute__((ext_vector_type(4))) float f32x4;
using short8 = __attribute__((ext_vector_type(8))) short;

// ---------------------------------------------------------------------------
// Numerics helpers
// ---------------------------------------------------------------------------

// fp32 -> e4m3fn -> fp32 round trip, RNE, handles subnormals (min 2^-9).
__device__ __forceinline__ float e4m3_rt(float f) {
    float a = fabsf(f);
    int e = (int)((__float_as_uint(a) >> 23)) - 127;
    if (e < -6) e = -6;                                 // e4m3 subnormal region
    float q    = __uint_as_float((unsigned)(e - 3 + 127) << 23);
    float qinv = __uint_as_float((unsigned)(3 - e + 127) << 23);
    float r = rintf(a * qinv) * q;                      // RNE to the e4m3 grid
    if (r > 448.0f) r = 448.0f;
    return copysignf(r, f);
}

// fp32 -> bf16 bits, RNE
__device__ __forceinline__ unsigned short f2bf(float f) {
    unsigned u = __float_as_uint(f);
    u += 0x7FFFu + ((u >> 16) & 1u);
    return (unsigned short)(u >> 16);
}

__device__ __forceinline__ void gload_lds16(const unsigned short* g, unsigned short* l) {
    __builtin_amdgcn_global_load_lds(
        (const __attribute__((address_space(1))) void*)g,
        (__attribute__((address_space(3))) void*)l,
        16, 0, 0);
}

#define BAR()   asm volatile("s_barrier" ::: "memory")
#define WAITK() do { asm volatile("s_waitcnt lgkmcnt(0)" ::: "memory"); \
                     __builtin_amdgcn_sched_barrier(0); } while (0)
#define VMW4()  asm volatile("s_waitcnt vmcnt(4)" ::: "memory")
#define VMW0()  asm volatile("s_waitcnt vmcnt(0)" ::: "memory")

// ---------------------------------------------------------------------------
// Conversion pre-passes (unchanged from round 1)
// ---------------------------------------------------------------------------

__global__ void cvt_x_kernel(const float* __restrict__ in,
                             unsigned short* __restrict__ outp, long n8) {
    long stride = (long)gridDim.x * blockDim.x;
    for (long i = (long)blockIdx.x * blockDim.x + threadIdx.x; i < n8; i += stride) {
        const float4* p = (const float4*)(in + i * 8);
        float4 v0 = p[0], v1 = p[1];
        uint4 o;
        o.x = (unsigned)f2bf(v0.x) | ((unsigned)f2bf(v0.y) << 16);
        o.y = (unsigned)f2bf(v0.z) | ((unsigned)f2bf(v0.w) << 16);
        o.z = (unsigned)f2bf(v1.x) | ((unsigned)f2bf(v1.y) << 16);
        o.w = (unsigned)f2bf(v1.z) | ((unsigned)f2bf(v1.w) << 16);
        *(uint4*)(outp + i * 8) = o;
    }
}

__global__ void cvt_w_kernel(const float* __restrict__ in,
                             unsigned short* __restrict__ outp, long n8) {
    long stride = (long)gridDim.x * blockDim.x;
    for (long i = (long)blockIdx.x * blockDim.x + threadIdx.x; i < n8; i += stride) {
        const float4* p = (const float4*)(in + i * 8);
        float4 v0 = p[0], v1 = p[1];
        uint4 o;
        o.x = (unsigned)f2bf(e4m3_rt(v0.x)) | ((unsigned)f2bf(e4m3_rt(v0.y)) << 16);
        o.y = (unsigned)f2bf(e4m3_rt(v0.z)) | ((unsigned)f2bf(e4m3_rt(v0.w)) << 16);
        o.z = (unsigned)f2bf(e4m3_rt(v1.x)) | ((unsigned)f2bf(e4m3_rt(v1.y)) << 16);
        o.w = (unsigned)f2bf(e4m3_rt(v1.z)) | ((unsigned)f2bf(e4m3_rt(v1.w)) << 16);
        *(uint4*)(outp + i * 8) = o;
    }
}

// ---------------------------------------------------------------------------
// 256x256 8-phase GEMM (m201 template, plain HIP).
//   8 waves (2M x 4N), per-wave output 128x64 = 8x4 fragments of 16x16x32.
//   LDS: 2 buffers x (A 256x64 + B 256x64) bf16 = 128 KiB, st_16x32 swizzle
//   (byte ^= ((byte>>9)&1)<<5  ==  colbyte ^= (row&4)<<3, rows are 128 B).
//   Swizzle applied on BOTH sides: inverse-swizzled global source for the
//   linear global_load_lds DMA + swizzled ds_read addresses (rule #21).
//   Per phase: {ds_read quadrant subtile | stage 1 half-tile} -> barrier ->
//   lgkmcnt(0) -> setprio(1) 16 MFMA setprio(0) -> [vmcnt(4) @ ph4/ph8] ->
//   barrier.  Counted vmcnt leaves 2 half-tiles (4 loads) in flight.
// ---------------------------------------------------------------------------

__global__ __launch_bounds__(512, 2)
void gemm_8ph_kernel(const unsigned short* __restrict__ A,
                     const unsigned short* __restrict__ Bw,
                     const float* __restrict__ bias,
                     float* __restrict__ C) {
    extern __shared__ char smem[];   // 131072 bytes

    // T1: XCD-aware swizzle (512 wgs % 8 == 0 -> simple form valid)
    int bid = blockIdx.x;
    int swz = (bid & 7) * 64 + (bid >> 3);
    int bm0 = (swz >> 4) * 256;   // 32 M-tiles
    int bn0 = (swz & 15) * 256;   // 16 N-tiles

    int tid = threadIdx.x;
    int l   = tid & 63;
    int w   = tid >> 6;     // 0..7
    int wr  = w >> 2;       // 0..1
    int wc  = w & 3;        // 0..3
    int l15 = l & 15;
    int hi  = l >> 4;       // 0..3

    // Swizzled ds_read byte offsets within a matrix buffer (excl. kk*2 term).
    unsigned aoff[8], boff[4];
#pragma unroll
    for (int m = 0; m < 8; ++m) {
        int r = wr * 128 + m * 16 + l15;
        aoff[m] = (unsigned)(r * 128 + ((hi * 16) ^ ((r & 4) << 3)));
    }
#pragma unroll
    for (int n = 0; n < 4; ++n) {
        int r = wc * 64 + n * 16 + l15;
        boff[n] = (unsigned)(r * 128 + ((hi * 16) ^ ((r & 4) << 3)));
    }

    // Staging: half-tile h (128 rows), 2 loads j. Per-lane global source is
    // inverse-swizzled; LDS dest is wave-uniform base (+ lane*16B by HW).
    const unsigned short* gA[4];
    const unsigned short* gB[4];
    unsigned ldso[4];
#pragma unroll
    for (int h = 0; h < 2; ++h)
#pragma unroll
        for (int j = 0; j < 2; ++j) {
            int r  = h * 128 + j * 64 + (tid >> 3);
            int cb = ((tid & 7) * 16) ^ ((r & 4) << 3);
            gA[h * 2 + j] = A  + (size_t)(bm0 + r) * K_DIM + (cb >> 1);
            gB[h * 2 + j] = Bw + (size_t)(bn0 + r) * K_DIM + (cb >> 1);
            ldso[h * 2 + j] = (unsigned)(h * 16384 + j * 8192 + w * 1024);
        }

#define STAGE_A(d, h, kt) do { \
    gload_lds16(gA[(h)*2+0] + (kt), (unsigned short*)(smem + (d)*65536 + ldso[(h)*2+0])); \
    gload_lds16(gA[(h)*2+1] + (kt), (unsigned short*)(smem + (d)*65536 + ldso[(h)*2+1])); } while (0)
#define STAGE_B(d, h, kt) do { \
    gload_lds16(gB[(h)*2+0] + (kt), (unsigned short*)(smem + (d)*65536 + 32768 + ldso[(h)*2+0])); \
    gload_lds16(gB[(h)*2+1] + (kt), (unsigned short*)(smem + (d)*65536 + 32768 + ldso[(h)*2+1])); } while (0)

    short8 a[4][2], b0f[2][2], b1f[2][2];
    f32x4 acc[8][4];
#pragma unroll
    for (int m = 0; m < 8; ++m)
#pragma unroll
        for (int n = 0; n < 4; ++n)
            acc[m][n] = (f32x4){0.f, 0.f, 0.f, 0.f};

    auto RDA = [&](int d, int mbase) {
#pragma unroll
        for (int m = 0; m < 4; ++m)
#pragma unroll
            for (int q = 0; q < 2; ++q)
                a[m][q] = *(const short8*)(smem + d * 65536 + aoff[mbase + m] + q * 64);
    };
    auto RDB = [&](int d, int nbase, short8 (&bf)[2][2]) {
#pragma unroll
        for (int n = 0; n < 2; ++n)
#pragma unroll
            for (int q = 0; q < 2; ++q)
                bf[n][q] = *(const short8*)(smem + d * 65536 + 32768 + boff[nbase + n] + q * 64);
    };
    auto MM = [&](int mbase, int nbase, short8 (&bf)[2][2]) {
        __builtin_amdgcn_s_setprio(1);
#pragma unroll
        for (int m = 0; m < 4; ++m)
#pragma unroll
            for (int n = 0; n < 2; ++n)
#pragma unroll
                for (int q = 0; q < 2; ++q)
                    acc[mbase + m][nbase + n] = __builtin_amdgcn_mfma_f32_16x16x32_bf16(
                        a[m][q], bf[n][q], acc[mbase + m][nbase + n], 0, 0, 0);
        __builtin_amdgcn_s_setprio(0);
    };

    // ---- Prologue: tile0 -> buf0 (8 loads), B halves of tile1 -> buf1 (4).
    STAGE_A(0, 0, 0);  STAGE_A(0, 1, 0);
    STAGE_B(0, 0, 0);  STAGE_B(0, 1, 0);
    STAGE_B(1, 0, 64); STAGE_B(1, 1, 64);
    VMW4();            // drain tile0's 8; leave B(1) x2 halves in flight
    BAR();

    // ---- Main loop: 31 steady iterations (tiles 0..61), 8 phases each.
    for (int i = 0; i < 31; ++i) {
        int k1 = (2 * i + 1) * 64, k2 = (2 * i + 2) * 64, k3 = (2 * i + 3) * 64;
        // ph1: rd A(m0-3)+B(n0-1) buf0 | stage A0(t+1)->buf1 | MM q(lo,lo)
        RDA(0, 0); RDB(0, 0, b0f); STAGE_A(1, 0, k1);
        BAR(); WAITK(); MM(0, 0, b0f); BAR();
        // ph2: rd B(n2-3) buf0 | stage A1(t+1)->buf1 | MM q(lo,hi)
        RDB(0, 2, b1f); STAGE_A(1, 1, k1);
        BAR(); WAITK(); MM(0, 2, b1f); BAR();
        // ph3: rd A(m4-7) buf0 | stage B0(t+2)->buf0 | MM q(hi,lo)
        RDA(0, 4); STAGE_B(0, 0, k2);
        BAR(); WAITK(); MM(4, 0, b0f); BAR();
        // ph4: stage B1(t+2)->buf0 | MM q(hi,hi) | vmcnt(4): tile t+1 landed
        STAGE_B(0, 1, k2);
        BAR(); WAITK(); MM(4, 2, b1f); VMW4(); BAR();
        // ph5: rd A(m0-3)+B(n0-1) buf1 | stage A0(t+2)->buf0 | MM
        RDA(1, 0); RDB(1, 0, b0f); STAGE_A(0, 0, k2);
        BAR(); WAITK(); MM(0, 0, b0f); BAR();
        // ph6: rd B(n2-3) buf1 | stage A1(t+2)->buf0 | MM
        RDB(1, 2, b1f); STAGE_A(0, 1, k2);
        BAR(); WAITK(); MM(0, 2, b1f); BAR();
        // ph7: rd A(m4-7) buf1 | stage B0(t+3)->buf1 | MM
        RDA(1, 4); STAGE_B(1, 0, k3);
        BAR(); WAITK(); MM(4, 0, b0f); BAR();
        // ph8: stage B1(t+3)->buf1 | MM | vmcnt(4): tile t+2 landed
        STAGE_B(1, 1, k3);
        BAR(); WAITK(); MM(4, 2, b1f); VMW4(); BAR();
    }

    // ---- Peeled last iteration (tiles 62, 63): only A halves of 63 staged.
    {
        int k1 = 63 * 64;
        RDA(0, 0); RDB(0, 0, b0f); STAGE_A(1, 0, k1);
        BAR(); WAITK(); MM(0, 0, b0f); BAR();
        RDB(0, 2, b1f); STAGE_A(1, 1, k1);
        BAR(); WAITK(); MM(0, 2, b1f); BAR();
        RDA(0, 4);
        BAR(); WAITK(); MM(4, 0, b0f); BAR();
        BAR(); WAITK(); MM(4, 2, b1f); VMW0(); BAR();
        RDA(1, 0); RDB(1, 0, b0f);
        BAR(); WAITK(); MM(0, 0, b0f); BAR();
        RDB(1, 2, b1f);
        BAR(); WAITK(); MM(0, 2, b1f); BAR();
        RDA(1, 4);
        BAR(); WAITK(); MM(4, 0, b0f); BAR();
        BAR(); WAITK(); MM(4, 2, b1f); BAR();
    }

    // ---- Epilogue: C/D layout col=l&15, row=(l>>4)*4+reg. Quantized bias.
    float bq[4];
#pragma unroll
    for (int n = 0; n < 4; ++n)
        bq[n] = e4m3_rt(bias[bn0 + wc * 64 + n * 16 + l15]);

#pragma unroll
    for (int m = 0; m < 8; ++m) {
        int orow = bm0 + wr * 128 + m * 16 + hi * 4;
#pragma unroll
        for (int n = 0; n < 4; ++n) {
            int ocol = bn0 + wc * 64 + n * 16 + l15;
#pragma unroll
            for (int j = 0; j < 4; ++j)
                C[(size_t)(orow + j) * N_DIM + ocol] = acc[m][n][j] + bq[n];
        }
    }
#undef STAGE_A
#undef STAGE_B
}

// ---------------------------------------------------------------------------
// Fallback (ws too small): simple fp32 LDS-tiled GEMM. Correctness insurance.
// ---------------------------------------------------------------------------

__global__ void fb_gemm_kernel(const float* __restrict__ A, const float* __restrict__ W,
                               const float* __restrict__ bias, float* __restrict__ C) {
    __shared__ float As[16][16];
    __shared__ float Ws[16][16];
    int tx = threadIdx.x & 15, ty = threadIdx.x >> 4;
    int row = blockIdx.y * 16 + ty;
    int col = blockIdx.x * 16 + tx;
    float acc = 0.f;
    for (int k0 = 0; k0 < K_DIM; k0 += 16) {
        As[ty][tx] = A[(size_t)row * K_DIM + k0 + tx];
        Ws[ty][tx] = e4m3_rt(W[(size_t)(blockIdx.x * 16 + ty) * K_DIM + k0 + tx]);
        __syncthreads();
#pragma unroll
        for (int kk = 0; kk < 16; ++kk)
            acc += As[ty][kk] * Ws[tx][kk];
        __syncthreads();
    }
    C[(size_t)row * N_DIM + col] = acc + e4m3_rt(bias[col]);
}

// ---------------------------------------------------------------------------

extern "C" void kernel_launch(void* const* d_in, const int* in_sizes, int n_in,
                              void* d_out, int out_size, void* d_ws, size_t ws_size,
                              hipStream_t stream) {
    const float* x  = (const float*)d_in[0];   // [8192, 4096] fp32
    const float* wt = (const float*)d_in[1];   // [4096, 4096] fp32
    const float* bi = (const float*)d_in[2];   // [4096] fp32
    float* out = (float*)d_out;

    const size_t needA = (size_t)M_DIM * K_DIM * 2;
    const size_t needW = (size_t)N_DIM * K_DIM * 2;

    if (ws_size >= needA + needW) {
        unsigned short* Abf = (unsigned short*)d_ws;
        unsigned short* Wbf = (unsigned short*)((char*)d_ws + needA);

        cvt_x_kernel<<<2048, 256, 0, stream>>>(x, Abf, (long)M_DIM * K_DIM / 8);
        cvt_w_kernel<<<2048, 256, 0, stream>>>(wt, Wbf, (long)N_DIM * K_DIM / 8);

        // 128 KiB dynamic LDS: raise the per-kernel cap (idempotent, host-side,
        // not a stream op -> safe under graph capture).
        (void)hipFuncSetAttribute((const void*)gemm_8ph_kernel,
                                  hipFuncAttributeMaxDynamicSharedMemorySize, 131072);

        dim3 grid((M_DIM / 256) * (N_DIM / 256));  // 512
        gemm_8ph_kernel<<<grid, 512, 131072, stream>>>(Abf, Wbf, bi, out);
    } else {
        dim3 grid(N_DIM / 16, M_DIM / 16);
        fb_gemm_kernel<<<grid, 256, 0, stream>>>(x, wt, bi, out);
    }
}